// Round 1
// baseline (82.241 us; speedup 1.0000x reference)
//
#include <hip/hip_runtime.h>
#include <hip/hip_bf16.h>

// CombinedLoss: 0.9*MSE + 0.1*pairwise-margin-ranking + 0.1*(1 - mean cos)
// Inputs: y (N fp32), labels (N fp32); output: 1 fp32 scalar.
//
// Margin term: sum_{i<j} max(0, -r*dy), r = sign-like of dl (ties -> sign(dy)).
// hinge(i,j) is symmetric and hinge(i,i)=0, so upper-tri sum = 0.5 * full sum.
// Per ordered pair: dl>0 -> relu(-dy); dl<0 -> relu(dy); dl==0 -> 0.

constexpr int BLOCK = 256;
constexpr int JT    = 32;   // number of j-chunks (gives IT*JT = 1024 blocks at N=8192)

#define EPS_F 1e-8f

__global__ __launch_bounds__(BLOCK) void combined_loss_pair_kernel(
    const float* __restrict__ y, const float* __restrict__ l, int N,
    float* __restrict__ hpart,   // [IT*JT] per-block hinge partial (ordered-pair sum)
    float* __restrict__ mpart,   // [IT]    per-i-tile MSE partial (written by jt==0 blocks)
    float* __restrict__ cpart)   // [IT]    per-i-tile cos partial
{
    __shared__ float sy[BLOCK];
    __shared__ float sl[BLOCK];
    __shared__ float red[BLOCK / 64];

    const int bx  = blockIdx.x;
    const int it  = bx / JT;
    const int jt  = bx % JT;
    const int tid = threadIdx.x;

    const int i    = it * BLOCK + tid;
    const bool valid = (i < N);
    const float yi = valid ? y[i] : 0.f;
    const float li = valid ? l[i] : 0.f;

    // j-range for this chunk
    const int chunk = (N + JT - 1) / JT;
    const int j0 = jt * chunk;
    const int j1 = min(N, j0 + chunk);

    float hsum = 0.f;
    for (int jb = j0; jb < j1; jb += BLOCK) {
        const int cnt = min(BLOCK, j1 - jb);
        if (tid < cnt) {
            sy[tid] = y[jb + tid];
            sl[tid] = l[jb + tid];
        }
        __syncthreads();
        if (valid) {
#pragma unroll 8
            for (int k = 0; k < cnt; ++k) {
                const float dl = li - sl[k];
                const float dy = yi - sy[k];
                // dl>0 -> relu(-dy); dl<0 -> relu(dy); dl==0 -> 0
                const float c = (dl > 0.f) ? fmaxf(-dy, 0.f)
                              : ((dl < 0.f) ? fmaxf(dy, 0.f) : 0.f);
                hsum += c;
            }
        }
        __syncthreads();
    }

    // ---- block reduce hsum ----
    for (int o = 32; o > 0; o >>= 1) hsum += __shfl_down(hsum, o, 64);
    const int lane = tid & 63, wid = tid >> 6;
    if (lane == 0) red[wid] = hsum;
    __syncthreads();
    if (tid == 0) {
        float s = 0.f;
        for (int w = 0; w < BLOCK / 64; ++w) s += red[w];
        hpart[bx] = s;
    }
    __syncthreads();

    // ---- linear terms: only jt==0 blocks, one element per thread ----
    if (jt == 0) {
        float m = 0.f, c = 0.f;
        if (valid) {
            const float d = yi - li;
            m = d * d;
            c = (yi * li) / (fmaxf(fabsf(yi), EPS_F) * fmaxf(fabsf(li), EPS_F));
        }
        for (int o = 32; o > 0; o >>= 1) {
            m += __shfl_down(m, o, 64);
            c += __shfl_down(c, o, 64);
        }
        if (lane == 0) red[wid] = m;
        __syncthreads();
        float msum = 0.f;
        if (tid == 0) for (int w = 0; w < BLOCK / 64; ++w) msum += red[w];
        __syncthreads();
        if (lane == 0) red[wid] = c;
        __syncthreads();
        if (tid == 0) {
            float csum = 0.f;
            for (int w = 0; w < BLOCK / 64; ++w) csum += red[w];
            mpart[it] = msum;
            cpart[it] = csum;
        }
    }
}

__global__ __launch_bounds__(256) void combined_loss_finalize_kernel(
    const float* __restrict__ hpart, const float* __restrict__ mpart,
    const float* __restrict__ cpart, int nh, int nm, int N,
    float* __restrict__ out)
{
    double h = 0.0, m = 0.0, c = 0.0;
    for (int k = threadIdx.x; k < nh; k += blockDim.x) h += (double)hpart[k];
    for (int k = threadIdx.x; k < nm; k += blockDim.x) {
        m += (double)mpart[k];
        c += (double)cpart[k];
    }
    for (int o = 32; o > 0; o >>= 1) {
        h += __shfl_down(h, o, 64);
        m += __shfl_down(m, o, 64);
        c += __shfl_down(c, o, 64);
    }
    __shared__ double sh[4][3];
    const int lane = threadIdx.x & 63, wid = threadIdx.x >> 6;
    if (lane == 0) { sh[wid][0] = h; sh[wid][1] = m; sh[wid][2] = c; }
    __syncthreads();
    if (threadIdx.x == 0) {
        double H = 0, M = 0, C = 0;
        for (int w = 0; w < 4; ++w) { H += sh[w][0]; M += sh[w][1]; C += sh[w][2]; }
        const double Nd = (double)N;
        const double mse    = M / Nd;
        const double pairs  = Nd * (Nd - 1.0) * 0.5;
        const double margin = (H * 0.5) / pairs;   // ordered-pair sum / 2 = upper-tri sum
        const double sim    = 1.0 - C / Nd;
        out[0] = (float)(0.9 * mse + 0.1 * margin + 0.1 * sim);
    }
}

extern "C" void kernel_launch(void* const* d_in, const int* in_sizes, int n_in,
                              void* d_out, int out_size, void* d_ws, size_t ws_size,
                              hipStream_t stream) {
    const float* y = (const float*)d_in[0];
    const float* l = (const float*)d_in[1];
    const int N = in_sizes[0];

    const int IT = (N + BLOCK - 1) / BLOCK;
    float* hpart = (float*)d_ws;
    float* mpart = hpart + (size_t)IT * JT;
    float* cpart = mpart + IT;

    combined_loss_pair_kernel<<<IT * JT, BLOCK, 0, stream>>>(y, l, N, hpart, mpart, cpart);
    combined_loss_finalize_kernel<<<1, 256, 0, stream>>>(hpart, mpart, cpart, IT * JT, IT, N,
                                                         (float*)d_out);
}

// Round 2
// 68.496 us; speedup vs baseline: 1.2007x; 1.2007x over previous
//
#include <hip/hip_runtime.h>
#include <hip/hip_bf16.h>

// CombinedLoss: 0.9*MSE + 0.1*margin-ranking + 0.1*(1 - mean cos), N fp32 pairs.
//
// Margin (upper-tri) = 0.5 * ordered-pair sum of relu(s*u),
//   u = yi - yj, s = sign(lj - li)  (ties contribute ~0, ignored).
// relu(s*u) = 0.5*(|u| + s*u)  ->  two accumulators:
//   A = sum |u|            (v_add with abs modifier)
//   B = sum (li<lj ? u : -u)  (cmp + cndmask + add)
// => 5 VALU per pair. M_PER=4 i's per thread amortizes LDS reads 4x.

constexpr int BLOCK = 256;
constexpr int M_PER = 4;                 // i's per thread
constexpr int ITILE = BLOCK * M_PER;     // 1024 i's per i-tile
constexpr int JCH   = 64;                // j's per block

#define EPS_F 1e-8f

__global__ __launch_bounds__(BLOCK) void combined_loss_pair_kernel(
    const float* __restrict__ y, const float* __restrict__ l, int N, int JT,
    float* __restrict__ hpart,   // [IT*JT] ordered-pair hinge partial per block
    float* __restrict__ mpart,   // [IT] MSE partial (jt==0 blocks)
    float* __restrict__ cpart)   // [IT] cos partial
{
    __shared__ float sy[JCH];
    __shared__ float sl[JCH];
    __shared__ float red[BLOCK / 64];

    const int bx  = blockIdx.x;
    const int it  = bx / JT;
    const int jt  = bx % JT;
    const int tid = threadIdx.x;

    float yi[M_PER], li[M_PER];
    bool  vm[M_PER];
#pragma unroll
    for (int m = 0; m < M_PER; ++m) {
        const int i = it * ITILE + m * BLOCK + tid;
        vm[m] = (i < N);
        yi[m] = vm[m] ? y[i] : 0.f;
        li[m] = vm[m] ? l[i] : 0.f;
    }

    const int j0   = jt * JCH;
    const int jcnt = min(JCH, N - j0);
    if (tid < JCH) {
        const bool vj = (tid < jcnt);
        sy[tid] = vj ? y[j0 + tid] : 0.f;
        sl[tid] = vj ? l[j0 + tid] : 0.f;
    }
    __syncthreads();

    float A[M_PER], B[M_PER];
#pragma unroll
    for (int m = 0; m < M_PER; ++m) { A[m] = 0.f; B[m] = 0.f; }

#define PROC(yj, lj)                                         \
    {                                                        \
        _Pragma("unroll")                                    \
        for (int m = 0; m < M_PER; ++m) {                    \
            const float u = yi[m] - (yj);                    \
            A[m] += fabsf(u);                                \
            B[m] += (li[m] < (lj)) ? u : -u;                 \
        }                                                    \
    }

    const int kv = jcnt & ~3;
#pragma unroll 4
    for (int k = 0; k < kv; k += 4) {
        const float4 y4 = *reinterpret_cast<const float4*>(&sy[k]);
        const float4 l4 = *reinterpret_cast<const float4*>(&sl[k]);
        PROC(y4.x, l4.x);
        PROC(y4.y, l4.y);
        PROC(y4.z, l4.z);
        PROC(y4.w, l4.w);
    }
    for (int k = kv; k < jcnt; ++k) PROC(sy[k], sl[k]);
#undef PROC

    // per-thread ordered-pair hinge sum (drop invalid i's)
    float h = 0.f;
#pragma unroll
    for (int m = 0; m < M_PER; ++m)
        if (vm[m]) h += 0.5f * (A[m] + B[m]);

    // ---- block reduce ----
    for (int o = 32; o > 0; o >>= 1) h += __shfl_down(h, o, 64);
    const int lane = tid & 63, wid = tid >> 6;
    if (lane == 0) red[wid] = h;
    __syncthreads();
    if (tid == 0) {
        float s = 0.f;
        for (int w = 0; w < BLOCK / 64; ++w) s += red[w];
        hpart[bx] = s;
    }
    __syncthreads();

    // ---- linear terms (MSE, cos): jt==0 blocks only ----
    if (jt == 0) {
        float msum = 0.f, csum = 0.f;
#pragma unroll
        for (int m = 0; m < M_PER; ++m) {
            if (vm[m]) {
                const float d = yi[m] - li[m];
                msum += d * d;
                csum += (yi[m] * li[m]) /
                        (fmaxf(fabsf(yi[m]), EPS_F) * fmaxf(fabsf(li[m]), EPS_F));
            }
        }
        for (int o = 32; o > 0; o >>= 1) {
            msum += __shfl_down(msum, o, 64);
            csum += __shfl_down(csum, o, 64);
        }
        if (lane == 0) red[wid] = msum;
        __syncthreads();
        float mtot = 0.f;
        if (tid == 0) for (int w = 0; w < BLOCK / 64; ++w) mtot += red[w];
        __syncthreads();
        if (lane == 0) red[wid] = csum;
        __syncthreads();
        if (tid == 0) {
            float ctot = 0.f;
            for (int w = 0; w < BLOCK / 64; ++w) ctot += red[w];
            mpart[it] = mtot;
            cpart[it] = ctot;
        }
    }
}

__global__ __launch_bounds__(256) void combined_loss_finalize_kernel(
    const float* __restrict__ hpart, const float* __restrict__ mpart,
    const float* __restrict__ cpart, int nh, int nm, int N,
    float* __restrict__ out)
{
    double h = 0.0, m = 0.0, c = 0.0;
    for (int k = threadIdx.x; k < nh; k += blockDim.x) h += (double)hpart[k];
    for (int k = threadIdx.x; k < nm; k += blockDim.x) {
        m += (double)mpart[k];
        c += (double)cpart[k];
    }
    for (int o = 32; o > 0; o >>= 1) {
        h += __shfl_down(h, o, 64);
        m += __shfl_down(m, o, 64);
        c += __shfl_down(c, o, 64);
    }
    __shared__ double sh[4][3];
    const int lane = threadIdx.x & 63, wid = threadIdx.x >> 6;
    if (lane == 0) { sh[wid][0] = h; sh[wid][1] = m; sh[wid][2] = c; }
    __syncthreads();
    if (threadIdx.x == 0) {
        double H = 0, M = 0, C = 0;
        for (int w = 0; w < 4; ++w) { H += sh[w][0]; M += sh[w][1]; C += sh[w][2]; }
        const double Nd     = (double)N;
        const double mse    = M / Nd;
        const double pairs  = Nd * (Nd - 1.0) * 0.5;
        const double margin = (H * 0.5) / pairs;  // ordered-sum/2 = upper-tri
        const double sim    = 1.0 - C / Nd;
        out[0] = (float)(0.9 * mse + 0.1 * margin + 0.1 * sim);
    }
}

extern "C" void kernel_launch(void* const* d_in, const int* in_sizes, int n_in,
                              void* d_out, int out_size, void* d_ws, size_t ws_size,
                              hipStream_t stream) {
    const float* y = (const float*)d_in[0];
    const float* l = (const float*)d_in[1];
    const int N = in_sizes[0];

    const int IT = (N + ITILE - 1) / ITILE;   // 8 at N=8192
    const int JT = (N + JCH - 1) / JCH;       // 128 at N=8192

    float* hpart = (float*)d_ws;
    float* mpart = hpart + (size_t)IT * JT;
    float* cpart = mpart + IT;

    combined_loss_pair_kernel<<<IT * JT, BLOCK, 0, stream>>>(y, l, N, JT,
                                                             hpart, mpart, cpart);
    combined_loss_finalize_kernel<<<1, 256, 0, stream>>>(hpart, mpart, cpart,
                                                         IT * JT, IT, N,
                                                         (float*)d_out);
}